// Round 5
// baseline (224.393 us; speedup 1.0000x reference)
//
#include <hip/hip_runtime.h>
#include <hip/hip_bf16.h>

#define BATCH 8
#define NN    2048
#define DD    64
#define BN    (BATCH * NN)          // 16384 rows

#define NSPLIT 8
#define JSPAN  (NN / NSPLIT)        // 256
#define KSTEPS (JSPAN / 32)         // 8 MFMA K-steps of 32 j each
#define HWST   264                  // hws row stride in ushorts (256 + 8 pad)

typedef __attribute__((ext_vector_type(8))) short bf16x8;
typedef __attribute__((ext_vector_type(4))) float f32x4;

// pack two fp32 into one dword of two RNE-rounded bf16 (lo, hi)
static __device__ __forceinline__ unsigned f2bf_pk(float lo, float hi) {
  unsigned ul = __float_as_uint(lo);
  unsigned uh = __float_as_uint(hi);
  ul = (ul + 0x7fffu + ((ul >> 16) & 1u)) >> 16;
  uh = (uh + 0x7fffu + ((uh >> 16) & 1u)) & 0xffff0000u;
  return ul | uh;
}

// -------------------------------------------------------------------------
// Kernel 1: hw = relu(h @ W); t1 = hw@a1; t2 = hw@a2; hwT = bf16 hw^T [b][k][j]
// grid = BN/32 = 512 blocks, 256 threads, 32 rows/block.
// -------------------------------------------------------------------------
__global__ __launch_bounds__(256) void k1_hw_t1_t2(
    const float* __restrict__ h, const float* __restrict__ W,
    const float* __restrict__ a1, const float* __restrict__ a2,
    unsigned short* __restrict__ hwT, float* __restrict__ t1, float* __restrict__ t2) {
  __shared__ float ht[64 * 36];          // h tile transposed [j][i<32], stride 36
  __shared__ float Ws[64 * 64];          // W row-major [j][k]
  __shared__ unsigned short bt[64 * 40]; // bf16 bounce [k][j<32], stride 40

  const int t  = threadIdx.x;
  const int r0 = blockIdx.x * 32;

#pragma unroll
  for (int r = 0; r < 4; ++r) {
    int f = t + 256 * r;
    reinterpret_cast<float4*>(Ws)[f] = reinterpret_cast<const float4*>(W)[f];
  }
#pragma unroll
  for (int r = 0; r < 2; ++r) {
    int f = t + 256 * r;
    int i = f >> 4, j4 = f & 15;
    float4 v = reinterpret_cast<const float4*>(h + (size_t)(r0 + i) * DD)[j4];
    ht[(4 * j4 + 0) * 36 + i] = v.x;
    ht[(4 * j4 + 1) * 36 + i] = v.y;
    ht[(4 * j4 + 2) * 36 + i] = v.z;
    ht[(4 * j4 + 3) * 36 + i] = v.w;
  }
  __syncthreads();

  const int trow = t >> 4, kcol = t & 15;
  float4 acc0 = make_float4(0.f, 0.f, 0.f, 0.f);
  float4 acc1 = make_float4(0.f, 0.f, 0.f, 0.f);

#pragma unroll 8
  for (int j = 0; j < 64; ++j) {
    float2 hv = *reinterpret_cast<const float2*>(&ht[j * 36 + 2 * trow]);
    float4 wv = reinterpret_cast<const float4*>(Ws)[j * 16 + kcol];
    acc0.x = fmaf(hv.x, wv.x, acc0.x); acc0.y = fmaf(hv.x, wv.y, acc0.y);
    acc0.z = fmaf(hv.x, wv.z, acc0.z); acc0.w = fmaf(hv.x, wv.w, acc0.w);
    acc1.x = fmaf(hv.y, wv.x, acc1.x); acc1.y = fmaf(hv.y, wv.y, acc1.y);
    acc1.z = fmaf(hv.y, wv.z, acc1.z); acc1.w = fmaf(hv.y, wv.w, acc1.w);
  }

  acc0.x = fmaxf(acc0.x, 0.f); acc0.y = fmaxf(acc0.y, 0.f);
  acc0.z = fmaxf(acc0.z, 0.f); acc0.w = fmaxf(acc0.w, 0.f);
  acc1.x = fmaxf(acc1.x, 0.f); acc1.y = fmaxf(acc1.y, 0.f);
  acc1.z = fmaxf(acc1.z, 0.f); acc1.w = fmaxf(acc1.w, 0.f);

  float4 a1v = reinterpret_cast<const float4*>(a1)[kcol];
  float4 a2v = reinterpret_cast<const float4*>(a2)[kcol];
  float s1_0 = acc0.x * a1v.x + acc0.y * a1v.y + acc0.z * a1v.z + acc0.w * a1v.w;
  float s1_1 = acc1.x * a1v.x + acc1.y * a1v.y + acc1.z * a1v.z + acc1.w * a1v.w;
  float s2_0 = acc0.x * a2v.x + acc0.y * a2v.y + acc0.z * a2v.z + acc0.w * a2v.w;
  float s2_1 = acc1.x * a2v.x + acc1.y * a2v.y + acc1.z * a2v.z + acc1.w * a2v.w;
#pragma unroll
  for (int m = 1; m <= 8; m <<= 1) {
    s1_0 += __shfl_xor(s1_0, m, 64);
    s1_1 += __shfl_xor(s1_1, m, 64);
    s2_0 += __shfl_xor(s2_0, m, 64);
    s2_1 += __shfl_xor(s2_1, m, 64);
  }
  {
    int row = r0 + 2 * trow;
    if (kcol == 0) {
      t1[row] = s1_0; t1[row + 1] = s1_1;
      t2[row] = s2_0; t2[row + 1] = s2_1;
    }
  }

  {
    const float* a0 = &acc0.x;
    const float* a1p = &acc1.x;
#pragma unroll
    for (int c = 0; c < 4; ++c) {
      int k = 4 * kcol + c;
      *reinterpret_cast<unsigned*>(&bt[k * 40 + 2 * trow]) = f2bf_pk(a0[c], a1p[c]);
    }
  }
  __syncthreads();
  {
    int k = t >> 2, jp = t & 3;
    int bb = r0 >> 11;          // batch
    int jb = r0 & (NN - 1);     // j base within batch
    *reinterpret_cast<int4*>(hwT + ((size_t)bb * DD + k) * NN + jb + jp * 8) =
        *reinterpret_cast<const int4*>(&bt[k * 40 + jp * 8]);
  }
}

// -------------------------------------------------------------------------
// Kernel 2: MFMA attention, NSPLIT=8 (JSPAN=256), register-lean.
// hws (64 k-rows x 256 j bf16, 34 KB) staged once; 4 blocks/CU, 16 waves/CU.
// j-loop: 8 fully-unrolled ks steps, adj software-pipelined ONE step ahead
// (only 4 int4 live). P generated in registers in A-frag layout:
//   lane m=lane&15 owns row i=i0+w*16+m; quad owns j=ks*32+quad*8+jj.
//   p = adj ? exp(relu(t1_i + t2_j)) : 1
// grid = NSPLIT*256 = 2048 blocks, 256 threads.
// -------------------------------------------------------------------------
__global__ __launch_bounds__(256, 4) void k2_attn(
    const unsigned short* __restrict__ hwT, const int* __restrict__ adj,
    const float* __restrict__ t1, const float* __restrict__ t2,
    float* __restrict__ pacc, float* __restrict__ pden) {
  __shared__ unsigned short hws[64 * HWST];  // 33.8 KB (reused as fp32 bounce)
  __shared__ float t2s[JSPAN];

  const int t     = threadIdx.x;
  const int split = blockIdx.x >> 8;
  const int rem   = blockIdx.x & 255;
  const int b     = rem >> 5;
  const int i0    = (rem & 31) * 64;
  const int w     = t >> 6;
  const int lane  = t & 63;
  const int m     = lane & 15;
  const int quad  = lane >> 4;
  const int jbase = split * JSPAN;

  // one-shot stage: hws[k][j] = hwT[b][k][jbase+j]  (coalesced int4)
  const unsigned short* hwTb = hwT + (size_t)b * DD * NN + jbase;
#pragma unroll
  for (int r = 0; r < 8; ++r) {
    int idx = t + 256 * r, k = idx >> 5, jp = idx & 31;
    *reinterpret_cast<int4*>(&hws[k * HWST + jp * 8]) =
        *reinterpret_cast<const int4*>(hwTb + (size_t)k * NN + jp * 8);
  }
  if (t < JSPAN / 4)
    *reinterpret_cast<float4*>(&t2s[t * 4]) =
        *reinterpret_cast<const float4*>(t2 + b * NN + jbase + t * 4);

  const float t1v = t1[b * NN + i0 + w * 16 + m];
  const int* adjl = adj + (size_t)(b * NN + i0 + w * 16 + m) * NN + jbase + quad * 8;

  f32x4 acc[4];
#pragma unroll
  for (int g = 0; g < 4; ++g) acc[g] = (f32x4){0.f, 0.f, 0.f, 0.f};
  float den = 0.f;

  // prime the 1-step adj pipeline
  int4 a0 = *reinterpret_cast<const int4*>(adjl);
  int4 a1i = *reinterpret_cast<const int4*>(adjl + 4);
  __syncthreads();   // hws + t2s ready (the ONLY barrier before the epilogue)

#pragma unroll
  for (int ks = 0; ks < KSTEPS; ++ks) {
    int4 n0, n1;
    if (ks + 1 < KSTEPS) {
      const int* ap = adjl + (ks + 1) * 32;
      n0 = *reinterpret_cast<const int4*>(ap);
      n1 = *reinterpret_cast<const int4*>(ap + 4);
    }

    const float* t2p = &t2s[ks * 32 + quad * 8];
    float4 e0 = *reinterpret_cast<const float4*>(t2p);
    float4 e1 = *reinterpret_cast<const float4*>(t2p + 4);
    float p0 = (a0.x > 0) ? __expf(fmaxf(t1v + e0.x, 0.f)) : 1.f;
    float p1 = (a0.y > 0) ? __expf(fmaxf(t1v + e0.y, 0.f)) : 1.f;
    float p2 = (a0.z > 0) ? __expf(fmaxf(t1v + e0.z, 0.f)) : 1.f;
    float p3 = (a0.w > 0) ? __expf(fmaxf(t1v + e0.w, 0.f)) : 1.f;
    float p4 = (a1i.x > 0) ? __expf(fmaxf(t1v + e1.x, 0.f)) : 1.f;
    float p5 = (a1i.y > 0) ? __expf(fmaxf(t1v + e1.y, 0.f)) : 1.f;
    float p6 = (a1i.z > 0) ? __expf(fmaxf(t1v + e1.z, 0.f)) : 1.f;
    float p7 = (a1i.w > 0) ? __expf(fmaxf(t1v + e1.w, 0.f)) : 1.f;
    den += ((p0 + p1) + (p2 + p3)) + ((p4 + p5) + (p6 + p7));

    union { bf16x8 v; unsigned u[4]; } Af;
    Af.u[0] = f2bf_pk(p0, p1);
    Af.u[1] = f2bf_pk(p2, p3);
    Af.u[2] = f2bf_pk(p4, p5);
    Af.u[3] = f2bf_pk(p6, p7);

#pragma unroll
    for (int g = 0; g < 4; ++g) {
      bf16x8 Bf = *reinterpret_cast<const bf16x8*>(
          &hws[(g * 16 + m) * HWST + ks * 32 + quad * 8]);
      acc[g] = __builtin_amdgcn_mfma_f32_16x16x32_bf16(Af.v, Bf, acc[g], 0, 0, 0);
    }

    a0 = n0; a1i = n1;
  }

  // den: each quad summed its own j subset -> reduce over quads
  den += __shfl_xor(den, 16, 64);
  den += __shfl_xor(den, 32, 64);

  const size_t sbase = (size_t)split * BN + (size_t)b * NN + i0;
  if (quad == 0) pden[sbase + w * 16 + m] = den;

  // coalesced pacc write via LDS bounce (reuse hws as fp32 [64][68])
  __syncthreads();
  float* os = reinterpret_cast<float*>(hws);
#pragma unroll
  for (int g = 0; g < 4; ++g)
#pragma unroll
    for (int r = 0; r < 4; ++r)
      os[(w * 16 + quad * 4 + r) * 68 + g * 16 + m] = acc[g][r];
  __syncthreads();
#pragma unroll
  for (int r2 = 0; r2 < 4; ++r2) {
    int idx = t + 256 * r2, row = idx >> 4, c4 = idx & 15;
    *reinterpret_cast<float4*>(&pacc[(sbase + row) * DD + c4 * 4]) =
        *reinterpret_cast<const float4*>(&os[row * 68 + c4 * 4]);
  }
}

// -------------------------------------------------------------------------
// Kernel 3: reduce partials + normalize + root-select + store.
// -------------------------------------------------------------------------
__global__ __launch_bounds__(256) void k3_reduce(
    const float* __restrict__ pacc, const float* __restrict__ pden,
    const float* __restrict__ h, const float* __restrict__ h_root,
    float* __restrict__ out) {
  const int g   = blockIdx.x * 256 + threadIdx.x;  // float4 index
  const int row = g >> 4;
  const int k4  = g & 15;

  float4 a = make_float4(0.f, 0.f, 0.f, 0.f);
  float den = 0.f;
#pragma unroll
  for (int s = 0; s < NSPLIT; ++s) {
    const size_t prow = (size_t)s * BN + row;
    float4 p = reinterpret_cast<const float4*>(pacc + prow * DD)[k4];
    a.x += p.x; a.y += p.y; a.z += p.z; a.w += p.w;
    den += pden[prow];
  }
  const float hr = h_root[row];
  float4 res;
  if (hr > 0.f) {
    const float inv = 1.f / den;
    res.x = a.x * inv; res.y = a.y * inv; res.z = a.z * inv; res.w = a.w * inv;
  } else {
    res = reinterpret_cast<const float4*>(h)[g];
  }
  reinterpret_cast<float4*>(out)[g] = res;
}

extern "C" void kernel_launch(void* const* d_in, const int* in_sizes, int n_in,
                              void* d_out, int out_size, void* d_ws, size_t ws_size,
                              hipStream_t stream) {
  const float* h      = (const float*)d_in[0];
  const int*   adj    = (const int*)d_in[1];
  const float* h_root = (const float*)d_in[2];
  const float* W      = (const float*)d_in[3];
  const float* a1     = (const float*)d_in[4];
  const float* a2     = (const float*)d_in[5];
  float* out = (float*)d_out;

  // workspace: hwT (bf16, BN*DD) | t1 | t2 | pacc[NSPLIT] | pden[NSPLIT]
  unsigned short* hwT = (unsigned short*)d_ws;
  float* t1 = (float*)(hwT + (size_t)BN * DD);
  float* t2 = t1 + BN;
  float* pacc = t2 + BN;
  float* pden = pacc + (size_t)NSPLIT * BN * DD;

  k1_hw_t1_t2<<<BN / 32, 256, 0, stream>>>(h, W, a1, a2, hwT, t1, t2);
  k2_attn<<<NSPLIT * 256, 256, 0, stream>>>(hwT, adj, t1, t2, pacc, pden);
  k3_reduce<<<(BN * DD / 4) / 256, 256, 0, stream>>>(pacc, pden, h, h_root, out);
}

// Round 6
// 217.357 us; speedup vs baseline: 1.0324x; 1.0324x over previous
//
#include <hip/hip_runtime.h>
#include <hip/hip_bf16.h>

#define BATCH 8
#define NN    2048
#define DD    64
#define BN    (BATCH * NN)          // 16384 rows

#define NSPLIT 8
#define JSPAN  (NN / NSPLIT)        // 256
#define KSTEPS (JSPAN / 32)         // 8 MFMA K-steps of 32 j each

typedef __attribute__((ext_vector_type(8))) short bf16x8;
typedef __attribute__((ext_vector_type(4))) float f32x4;

// pack two fp32 into one dword of two RNE-rounded bf16 (lo, hi)
static __device__ __forceinline__ unsigned f2bf_pk(float lo, float hi) {
  unsigned ul = __float_as_uint(lo);
  unsigned uh = __float_as_uint(hi);
  ul = (ul + 0x7fffu + ((ul >> 16) & 1u)) >> 16;
  uh = (uh + 0x7fffu + ((uh >> 16) & 1u)) & 0xffff0000u;
  return ul | uh;
}

// -------------------------------------------------------------------------
// Kernel 1: hw = relu(h @ W); t1 = hw@a1; t2 = hw@a2; hwT = bf16 hw^T [b][k][j]
// grid = BN/32 = 512 blocks, 256 threads, 32 rows/block.
// -------------------------------------------------------------------------
__global__ __launch_bounds__(256) void k1_hw_t1_t2(
    const float* __restrict__ h, const float* __restrict__ W,
    const float* __restrict__ a1, const float* __restrict__ a2,
    unsigned short* __restrict__ hwT, float* __restrict__ t1, float* __restrict__ t2) {
  __shared__ float ht[64 * 36];          // h tile transposed [j][i<32], stride 36
  __shared__ float Ws[64 * 64];          // W row-major [j][k]
  __shared__ unsigned short bt[64 * 40]; // bf16 bounce [k][j<32], stride 40

  const int t  = threadIdx.x;
  const int r0 = blockIdx.x * 32;

#pragma unroll
  for (int r = 0; r < 4; ++r) {
    int f = t + 256 * r;
    reinterpret_cast<float4*>(Ws)[f] = reinterpret_cast<const float4*>(W)[f];
  }
#pragma unroll
  for (int r = 0; r < 2; ++r) {
    int f = t + 256 * r;
    int i = f >> 4, j4 = f & 15;
    float4 v = reinterpret_cast<const float4*>(h + (size_t)(r0 + i) * DD)[j4];
    ht[(4 * j4 + 0) * 36 + i] = v.x;
    ht[(4 * j4 + 1) * 36 + i] = v.y;
    ht[(4 * j4 + 2) * 36 + i] = v.z;
    ht[(4 * j4 + 3) * 36 + i] = v.w;
  }
  __syncthreads();

  const int trow = t >> 4, kcol = t & 15;
  float4 acc0 = make_float4(0.f, 0.f, 0.f, 0.f);
  float4 acc1 = make_float4(0.f, 0.f, 0.f, 0.f);

#pragma unroll 8
  for (int j = 0; j < 64; ++j) {
    float2 hv = *reinterpret_cast<const float2*>(&ht[j * 36 + 2 * trow]);
    float4 wv = reinterpret_cast<const float4*>(Ws)[j * 16 + kcol];
    acc0.x = fmaf(hv.x, wv.x, acc0.x); acc0.y = fmaf(hv.x, wv.y, acc0.y);
    acc0.z = fmaf(hv.x, wv.z, acc0.z); acc0.w = fmaf(hv.x, wv.w, acc0.w);
    acc1.x = fmaf(hv.y, wv.x, acc1.x); acc1.y = fmaf(hv.y, wv.y, acc1.y);
    acc1.z = fmaf(hv.y, wv.z, acc1.z); acc1.w = fmaf(hv.y, wv.w, acc1.w);
  }

  acc0.x = fmaxf(acc0.x, 0.f); acc0.y = fmaxf(acc0.y, 0.f);
  acc0.z = fmaxf(acc0.z, 0.f); acc0.w = fmaxf(acc0.w, 0.f);
  acc1.x = fmaxf(acc1.x, 0.f); acc1.y = fmaxf(acc1.y, 0.f);
  acc1.z = fmaxf(acc1.z, 0.f); acc1.w = fmaxf(acc1.w, 0.f);

  float4 a1v = reinterpret_cast<const float4*>(a1)[kcol];
  float4 a2v = reinterpret_cast<const float4*>(a2)[kcol];
  float s1_0 = acc0.x * a1v.x + acc0.y * a1v.y + acc0.z * a1v.z + acc0.w * a1v.w;
  float s1_1 = acc1.x * a1v.x + acc1.y * a1v.y + acc1.z * a1v.z + acc1.w * a1v.w;
  float s2_0 = acc0.x * a2v.x + acc0.y * a2v.y + acc0.z * a2v.z + acc0.w * a2v.w;
  float s2_1 = acc1.x * a2v.x + acc1.y * a2v.y + acc1.z * a2v.z + acc1.w * a2v.w;
#pragma unroll
  for (int m = 1; m <= 8; m <<= 1) {
    s1_0 += __shfl_xor(s1_0, m, 64);
    s1_1 += __shfl_xor(s1_1, m, 64);
    s2_0 += __shfl_xor(s2_0, m, 64);
    s2_1 += __shfl_xor(s2_1, m, 64);
  }
  {
    int row = r0 + 2 * trow;
    if (kcol == 0) {
      t1[row] = s1_0; t1[row + 1] = s1_1;
      t2[row] = s2_0; t2[row + 1] = s2_1;
    }
  }

  {
    const float* a0 = &acc0.x;
    const float* a1p = &acc1.x;
#pragma unroll
    for (int c = 0; c < 4; ++c) {
      int k = 4 * kcol + c;
      *reinterpret_cast<unsigned*>(&bt[k * 40 + 2 * trow]) = f2bf_pk(a0[c], a1p[c]);
    }
  }
  __syncthreads();
  {
    int k = t >> 2, jp = t & 3;
    int bb = r0 >> 11;          // batch
    int jb = r0 & (NN - 1);     // j base within batch
    *reinterpret_cast<int4*>(hwT + ((size_t)bb * DD + k) * NN + jb + jp * 8) =
        *reinterpret_cast<const int4*>(&bt[k * 40 + jp * 8]);
  }
}

// -------------------------------------------------------------------------
// Kernel 2: MFMA attention, no LDS-B, register-lean, root-skip.
// Each wave: 2 i-tiles (32 rows), jspan 256. A-frag (P) generated in regs:
//   lane m owns rows i0+m / i0+16+m; quad owns j = ks*32 + quad*8 + jj.
//   p = adj ? exp(relu(t1_i + t2_j)) : 1 ; rows with h_root<=0 skip adj loads
//   (their outputs are replaced by h0 in k3 anyway).
// B-frags: direct global int4 loads from hwT (2 MB, L2-resident), shared
// between the wave's two i-tiles. No barriers after t2s stage. unroll-1
// j-loop + 1-step adj prefetch keeps VGPRs ~120 (no scratch spill).
// grid = NSPLIT*128 = 1024 blocks (4/CU), 256 threads.
// -------------------------------------------------------------------------
__global__ __launch_bounds__(256, 4) void k2_attn(
    const unsigned short* __restrict__ hwT, const int* __restrict__ adj,
    const float* __restrict__ t1, const float* __restrict__ t2,
    const float* __restrict__ h_root,
    float* __restrict__ pacc, float* __restrict__ pden) {
  __shared__ float t2s[JSPAN];   // 1 KB

  const int t     = threadIdx.x;
  const int split = blockIdx.x >> 7;     // 0..7
  const int rem   = blockIdx.x & 127;
  const int b     = rem >> 4;            // 0..7
  const int i0    = (rem & 15) * 128 + (t >> 6) * 32;  // wave's 32-row base
  const int lane  = t & 63;
  const int m     = lane & 15;
  const int quad  = lane >> 4;
  const int jbase = split * JSPAN;

  if (t < JSPAN / 4)
    *reinterpret_cast<float4*>(&t2s[t * 4]) =
        *reinterpret_cast<const float4*>(t2 + b * NN + jbase + t * 4);

  const int rowbase = b * NN + i0;
  const float t1v0 = t1[rowbase + m];
  const float t1v1 = t1[rowbase + 16 + m];
  const bool  do0  = h_root[rowbase + m] > 0.f;
  const bool  do1  = h_root[rowbase + 16 + m] > 0.f;
  const int* adj0 = adj + (size_t)(rowbase + m) * NN + jbase + quad * 8;
  const int* adj1 = adj + (size_t)(rowbase + 16 + m) * NN + jbase + quad * 8;
  const unsigned short* hwp = hwT + (size_t)b * DD * NN + jbase + quad * 8 + m * NN;

  f32x4 acc0[4], acc1[4];
#pragma unroll
  for (int g = 0; g < 4; ++g) {
    acc0[g] = (f32x4){0.f, 0.f, 0.f, 0.f};
    acc1[g] = (f32x4){0.f, 0.f, 0.f, 0.f};
  }
  float den0 = 0.f, den1 = 0.f;

  // prime 1-step adj pipeline (predicated per-lane on root flag)
  int4 c00 = make_int4(0, 0, 0, 0), c01 = c00, c10 = c00, c11 = c00;
  if (do0) { c00 = *reinterpret_cast<const int4*>(adj0);
             c01 = *reinterpret_cast<const int4*>(adj0 + 4); }
  if (do1) { c10 = *reinterpret_cast<const int4*>(adj1);
             c11 = *reinterpret_cast<const int4*>(adj1 + 4); }

  __syncthreads();   // t2s ready

#pragma unroll 1
  for (int ks = 0; ks < KSTEPS; ++ks) {
    int4 n00 = make_int4(0, 0, 0, 0), n01 = n00, n10 = n00, n11 = n00;
    if (ks + 1 < KSTEPS) {
      const int* a0p = adj0 + (ks + 1) * 32;
      const int* a1p = adj1 + (ks + 1) * 32;
      if (do0) { n00 = *reinterpret_cast<const int4*>(a0p);
                 n01 = *reinterpret_cast<const int4*>(a0p + 4); }
      if (do1) { n10 = *reinterpret_cast<const int4*>(a1p);
                 n11 = *reinterpret_cast<const int4*>(a1p + 4); }
    }

    // B-frags: issue early (L2 latency overlaps the exp work below)
    bf16x8 B0 = *reinterpret_cast<const bf16x8*>(hwp + 0 * 16 * NN + ks * 32);
    bf16x8 B1 = *reinterpret_cast<const bf16x8*>(hwp + 1 * 16 * NN + ks * 32);
    bf16x8 B2 = *reinterpret_cast<const bf16x8*>(hwp + 2 * 16 * NN + ks * 32);
    bf16x8 B3 = *reinterpret_cast<const bf16x8*>(hwp + 3 * 16 * NN + ks * 32);

    const float* t2p = &t2s[ks * 32 + quad * 8];
    float4 e0 = *reinterpret_cast<const float4*>(t2p);
    float4 e1 = *reinterpret_cast<const float4*>(t2p + 4);

    union { bf16x8 v; unsigned u[4]; } Af0, Af1;
    {
      float p0 = (c00.x > 0) ? __expf(fmaxf(t1v0 + e0.x, 0.f)) : 1.f;
      float p1 = (c00.y > 0) ? __expf(fmaxf(t1v0 + e0.y, 0.f)) : 1.f;
      float p2 = (c00.z > 0) ? __expf(fmaxf(t1v0 + e0.z, 0.f)) : 1.f;
      float p3 = (c00.w > 0) ? __expf(fmaxf(t1v0 + e0.w, 0.f)) : 1.f;
      float p4 = (c01.x > 0) ? __expf(fmaxf(t1v0 + e1.x, 0.f)) : 1.f;
      float p5 = (c01.y > 0) ? __expf(fmaxf(t1v0 + e1.y, 0.f)) : 1.f;
      float p6 = (c01.z > 0) ? __expf(fmaxf(t1v0 + e1.z, 0.f)) : 1.f;
      float p7 = (c01.w > 0) ? __expf(fmaxf(t1v0 + e1.w, 0.f)) : 1.f;
      den0 += ((p0 + p1) + (p2 + p3)) + ((p4 + p5) + (p6 + p7));
      Af0.u[0] = f2bf_pk(p0, p1); Af0.u[1] = f2bf_pk(p2, p3);
      Af0.u[2] = f2bf_pk(p4, p5); Af0.u[3] = f2bf_pk(p6, p7);
    }
    {
      float p0 = (c10.x > 0) ? __expf(fmaxf(t1v1 + e0.x, 0.f)) : 1.f;
      float p1 = (c10.y > 0) ? __expf(fmaxf(t1v1 + e0.y, 0.f)) : 1.f;
      float p2 = (c10.z > 0) ? __expf(fmaxf(t1v1 + e0.z, 0.f)) : 1.f;
      float p3 = (c10.w > 0) ? __expf(fmaxf(t1v1 + e0.w, 0.f)) : 1.f;
      float p4 = (c11.x > 0) ? __expf(fmaxf(t1v1 + e1.x, 0.f)) : 1.f;
      float p5 = (c11.y > 0) ? __expf(fmaxf(t1v1 + e1.y, 0.f)) : 1.f;
      float p6 = (c11.z > 0) ? __expf(fmaxf(t1v1 + e1.z, 0.f)) : 1.f;
      float p7 = (c11.w > 0) ? __expf(fmaxf(t1v1 + e1.w, 0.f)) : 1.f;
      den1 += ((p0 + p1) + (p2 + p3)) + ((p4 + p5) + (p6 + p7));
      Af1.u[0] = f2bf_pk(p0, p1); Af1.u[1] = f2bf_pk(p2, p3);
      Af1.u[2] = f2bf_pk(p4, p5); Af1.u[3] = f2bf_pk(p6, p7);
    }

    acc0[0] = __builtin_amdgcn_mfma_f32_16x16x32_bf16(Af0.v, B0, acc0[0], 0, 0, 0);
    acc0[1] = __builtin_amdgcn_mfma_f32_16x16x32_bf16(Af0.v, B1, acc0[1], 0, 0, 0);
    acc0[2] = __builtin_amdgcn_mfma_f32_16x16x32_bf16(Af0.v, B2, acc0[2], 0, 0, 0);
    acc0[3] = __builtin_amdgcn_mfma_f32_16x16x32_bf16(Af0.v, B3, acc0[3], 0, 0, 0);
    acc1[0] = __builtin_amdgcn_mfma_f32_16x16x32_bf16(Af1.v, B0, acc1[0], 0, 0, 0);
    acc1[1] = __builtin_amdgcn_mfma_f32_16x16x32_bf16(Af1.v, B1, acc1[1], 0, 0, 0);
    acc1[2] = __builtin_amdgcn_mfma_f32_16x16x32_bf16(Af1.v, B2, acc1[2], 0, 0, 0);
    acc1[3] = __builtin_amdgcn_mfma_f32_16x16x32_bf16(Af1.v, B3, acc1[3], 0, 0, 0);

    c00 = n00; c01 = n01; c10 = n10; c11 = n11;
  }

  // den: each quad summed its own j subset -> reduce over quads
  den0 += __shfl_xor(den0, 16, 64);
  den0 += __shfl_xor(den0, 32, 64);
  den1 += __shfl_xor(den1, 16, 64);
  den1 += __shfl_xor(den1, 32, 64);

  const size_t sbase = (size_t)split * BN + rowbase;
  if (quad == 0) {
    pden[sbase + m] = den0;
    pden[sbase + 16 + m] = den1;
  }

  // direct stores: col g*16+m consecutive over 16 m-lanes (64 B segments)
#pragma unroll
  for (int g = 0; g < 4; ++g)
#pragma unroll
    for (int r = 0; r < 4; ++r) {
      pacc[(sbase + quad * 4 + r) * DD + g * 16 + m] = acc0[g][r];
      pacc[(sbase + 16 + quad * 4 + r) * DD + g * 16 + m] = acc1[g][r];
    }
}

// -------------------------------------------------------------------------
// Kernel 3: reduce partials + normalize + root-select + store.
// -------------------------------------------------------------------------
__global__ __launch_bounds__(256) void k3_reduce(
    const float* __restrict__ pacc, const float* __restrict__ pden,
    const float* __restrict__ h, const float* __restrict__ h_root,
    float* __restrict__ out) {
  const int g   = blockIdx.x * 256 + threadIdx.x;  // float4 index
  const int row = g >> 4;
  const int k4  = g & 15;

  float4 a = make_float4(0.f, 0.f, 0.f, 0.f);
  float den = 0.f;
#pragma unroll
  for (int s = 0; s < NSPLIT; ++s) {
    const size_t prow = (size_t)s * BN + row;
    float4 p = reinterpret_cast<const float4*>(pacc + prow * DD)[k4];
    a.x += p.x; a.y += p.y; a.z += p.z; a.w += p.w;
    den += pden[prow];
  }
  const float hr = h_root[row];
  float4 res;
  if (hr > 0.f) {
    const float inv = 1.f / den;
    res.x = a.x * inv; res.y = a.y * inv; res.z = a.z * inv; res.w = a.w * inv;
  } else {
    res = reinterpret_cast<const float4*>(h)[g];
  }
  reinterpret_cast<float4*>(out)[g] = res;
}

extern "C" void kernel_launch(void* const* d_in, const int* in_sizes, int n_in,
                              void* d_out, int out_size, void* d_ws, size_t ws_size,
                              hipStream_t stream) {
  const float* h      = (const float*)d_in[0];
  const int*   adj    = (const int*)d_in[1];
  const float* h_root = (const float*)d_in[2];
  const float* W      = (const float*)d_in[3];
  const float* a1     = (const float*)d_in[4];
  const float* a2     = (const float*)d_in[5];
  float* out = (float*)d_out;

  // workspace: hwT (bf16, BN*DD) | t1 | t2 | pacc[NSPLIT] | pden[NSPLIT]
  unsigned short* hwT = (unsigned short*)d_ws;
  float* t1 = (float*)(hwT + (size_t)BN * DD);
  float* t2 = t1 + BN;
  float* pacc = t2 + BN;
  float* pden = pacc + (size_t)NSPLIT * BN * DD;

  k1_hw_t1_t2<<<BN / 32, 256, 0, stream>>>(h, W, a1, a2, hwT, t1, t2);
  k2_attn<<<NSPLIT * 128, 256, 0, stream>>>(hwT, adj, t1, t2, h_root, pacc, pden);
  k3_reduce<<<(BN * DD / 4) / 256, 256, 0, stream>>>(pacc, pden, h, h_root, out);
}